// Round 13
// baseline (238.227 us; speedup 1.0000x reference)
//
#include <hip/hip_runtime.h>
#include <hip/hip_bf16.h>
#include <cstdint>
#include <cstddef>

typedef __attribute__((ext_vector_type(8))) short short8;
typedef __attribute__((ext_vector_type(4))) float f32x4;
typedef __attribute__((ext_vector_type(16))) float f32x16;
typedef unsigned int u32;
typedef unsigned short u16;

// ---------- helpers ----------
__device__ inline u16 f2b(float x) {
    union { float f; u32 u; } v; v.f = x;
    u32 u = v.u;
    u32 r = (u + 0x7fff + ((u >> 16) & 1)) >> 16;
    return (u16)r;
}
__device__ inline float b2f(u16 h) {
    union { u32 u; float f; } v; v.u = ((u32)h) << 16;
    return v.f;
}
__device__ inline u32 cvtpk(float lo, float hi) {
    u32 r; asm("v_cvt_pk_bf16_f32 %0, %1, %2" : "=v"(r) : "v"(lo), "v"(hi)); return r;
}
__device__ inline float ex2(float x) {   // raw v_exp_f32: D = 2^S0
    float r; asm("v_exp_f32 %0, %1" : "=v"(r) : "v"(x)); return r;
}
__device__ inline void gll16(const void* g, void* l) {
    __builtin_amdgcn_global_load_lds(
        (const __attribute__((address_space(1))) void*)g,
        (__attribute__((address_space(3))) void*)l, 16, 0, 0);
}

// ---------- tiled weight repacks ----------
__global__ __launch_bounds__(256) void repack_qkv_tiled(
    const float* __restrict__ Wq, const float* __restrict__ Wk, const float* __restrict__ Wv,
    u16* __restrict__ out)
{
    __shared__ u16 lds[64 * 72];
    const int tid = threadIdx.x;
    const int c0 = blockIdx.x * 64;
    const int sh = blockIdx.y;
    const int sel = sh >> 4, h = sh & 15;
    const float* W = (sel == 0) ? Wq : (sel == 1) ? Wk : Wv;
    #pragma unroll
    for (int it = 0; it < 4; ++it) {
        int idx = tid + it * 256;
        int c = idx >> 4, d4 = idx & 15;
        float4 v = *reinterpret_cast<const float4*>(&W[((size_t)(h * 1024 + c0 + c)) * 64 + d4 * 4]);
        lds[(d4 * 4 + 0) * 72 + c] = f2b(v.x);
        lds[(d4 * 4 + 1) * 72 + c] = f2b(v.y);
        lds[(d4 * 4 + 2) * 72 + c] = f2b(v.z);
        lds[(d4 * 4 + 3) * 72 + c] = f2b(v.w);
    }
    __syncthreads();
    #pragma unroll
    for (int it = 0; it < 2; ++it) {
        int idx = tid + it * 256;
        int d = idx >> 3, c8 = idx & 7;
        short8 s = *reinterpret_cast<const short8*>(&lds[d * 72 + c8 * 8]);
        *reinterpret_cast<short8*>(&out[((size_t)(sel * 1024 + h * 64 + d)) * 1024 + c0 + c8 * 8]) = s;
    }
}

__global__ __launch_bounds__(256) void trans_tiled(
    const float* __restrict__ in, u16* __restrict__ out, int P, int Q)
{
    __shared__ u16 lds[64 * 72];
    const int tid = threadIdx.x;
    const int p0 = blockIdx.x * 64, q0 = blockIdx.y * 64;
    #pragma unroll
    for (int it = 0; it < 4; ++it) {
        int idx = tid + it * 256;
        int p = idx >> 4, q4 = idx & 15;
        float4 v = *reinterpret_cast<const float4*>(&in[(size_t)(p0 + p) * Q + q0 + q4 * 4]);
        lds[(q4 * 4 + 0) * 72 + p] = f2b(v.x);
        lds[(q4 * 4 + 1) * 72 + p] = f2b(v.y);
        lds[(q4 * 4 + 2) * 72 + p] = f2b(v.z);
        lds[(q4 * 4 + 3) * 72 + p] = f2b(v.w);
    }
    __syncthreads();
    #pragma unroll
    for (int it = 0; it < 2; ++it) {
        int idx = tid + it * 256;
        int q = idx >> 3, p8 = idx & 7;
        short8 s = *reinterpret_cast<const short8*>(&lds[q * 72 + p8 * 8]);
        *reinterpret_cast<short8*>(&out[(size_t)(q0 + q) * P + p0 + p8 * 8]) = s;
    }
}

// Vt[b][h][d=64][s=2048] bf16 from qkv V region
__global__ __launch_bounds__(256) void vt_kernel(
    const u16* __restrict__ qkv, u16* __restrict__ vt)
{
    __shared__ u16 lds[64 * 72];
    const int tid = threadIdx.x;
    const int s0 = blockIdx.x * 64, h = blockIdx.y, b = blockIdx.z;
    #pragma unroll
    for (int it = 0; it < 2; ++it) {
        int idx = tid + it * 256;
        int s = idx >> 3, d8 = idx & 7;
        short8 kv = *reinterpret_cast<const short8*>(
            &qkv[((size_t)(b * 2048 + s0 + s)) * 3072 + 2048 + h * 64 + d8 * 8]);
        #pragma unroll
        for (int j = 0; j < 8; ++j) lds[(d8 * 8 + j) * 72 + s] = (u16)kv[j];
    }
    __syncthreads();
    #pragma unroll
    for (int it = 0; it < 2; ++it) {
        int idx = tid + it * 256;
        int d = idx >> 3, s8 = idx & 7;
        short8 s = *reinterpret_cast<const short8*>(&lds[d * 72 + s8 * 8]);
        *reinterpret_cast<short8*>(&vt[((size_t)(b * 16 + h) * 64 + d) * 2048 + s0 + s8 * 8]) = s;
    }
}

// ---------- layernorm ----------
__global__ __launch_bounds__(256) void ln_kernel(
    const float* __restrict__ x, const float* __restrict__ g, const float* __restrict__ be,
    float* __restrict__ yf, u16* __restrict__ yb)
{
    int row = blockIdx.x;
    const float4 v = reinterpret_cast<const float4*>(x + (size_t)row * 1024)[threadIdx.x];
    float s  = v.x + v.y + v.z + v.w;
    float s2 = v.x * v.x + v.y * v.y + v.z * v.z + v.w * v.w;
    #pragma unroll
    for (int o = 32; o >= 1; o >>= 1) { s += __shfl_xor(s, o); s2 += __shfl_xor(s2, o); }
    __shared__ float red[8];
    int w = threadIdx.x >> 6;
    if ((threadIdx.x & 63) == 0) { red[w] = s; red[4 + w] = s2; }
    __syncthreads();
    s  = red[0] + red[1] + red[2] + red[3];
    s2 = red[4] + red[5] + red[6] + red[7];
    float mu = s * (1.0f / 1024.0f);
    float var = s2 * (1.0f / 1024.0f) - mu * mu;
    float rs = rsqrtf(var + 1e-5f);
    const float4 gg = reinterpret_cast<const float4*>(g)[threadIdx.x];
    const float4 bb = reinterpret_cast<const float4*>(be)[threadIdx.x];
    float4 o;
    o.x = (v.x - mu) * rs * gg.x + bb.x;
    o.y = (v.y - mu) * rs * gg.y + bb.y;
    o.z = (v.z - mu) * rs * gg.z + bb.z;
    o.w = (v.w - mu) * rs * gg.w + bb.w;
    reinterpret_cast<float4*>(yf + (size_t)row * 1024)[threadIdx.x] = o;
    uint2 pk;
    pk.x = (u32)f2b(o.x) | ((u32)f2b(o.y) << 16);
    pk.y = (u32)f2b(o.z) | ((u32)f2b(o.w) << 16);
    reinterpret_cast<uint2*>(yb + (size_t)row * 1024)[threadIdx.x] = pk;
}

// ---------- GEMM 128x128, dbuf + counted vmcnt(8) ----------
template<bool BIAS, bool RELU, bool RESID, bool OUTB>
__global__ __launch_bounds__(256) void gemm_bt(
    const u16* __restrict__ A, int lda,
    const u16* __restrict__ BT, int ldb,
    void* __restrict__ out, int ldo,
    const float* __restrict__ bias,
    const float* __restrict__ resid,
    int K)
{
    __shared__ __align__(16) char smem[64 * 1024];
    const int tid = threadIdx.x;
    const int lane = tid & 63, w = tid >> 6;
    const int wr = w >> 1, wc = w & 1;
    const int l15 = lane & 15, lq = lane >> 4;

    const int nx = gridDim.x;
    const int nwg = nx * gridDim.y;
    int orig = blockIdx.y * nx + blockIdx.x;
    int wgid = orig;
    if ((nwg & 7) == 0) wgid = (orig & 7) * (nwg >> 3) + (orig >> 3);
    const int m0 = (wgid / nx) * 128, n0 = (wgid % nx) * 128;

    auto stage = [&](int kt, int buf) {
        char* As = smem + buf * 32768;
        char* Bs = smem + buf * 32768 + 16384;
        #pragma unroll
        for (int it = 0; it < 4; ++it) {
            int slot = it * 256 + tid;
            int row = slot >> 3, c8 = (slot & 7) ^ (row & 7);
            gll16(A + (size_t)(m0 + row) * lda + kt + c8 * 8, As + (it * 256 + w * 64) * 16);
        }
        #pragma unroll
        for (int it = 0; it < 4; ++it) {
            int slot = it * 256 + tid;
            int row = slot >> 3, c8 = (slot & 7) ^ (row & 7);
            gll16(BT + (size_t)(n0 + row) * ldb + kt + c8 * 8, Bs + (it * 256 + w * 64) * 16);
        }
    };

    f32x4 acc[4][4] = {};
    const int nk = K >> 6;

    stage(0, 0);
    asm volatile("s_waitcnt vmcnt(0)" ::: "memory");
    __builtin_amdgcn_s_barrier();

    for (int t = 0; t < nk; ++t) {
        const char* As = smem + (t & 1) * 32768;
        const char* Bs = smem + (t & 1) * 32768 + 16384;
        if (t + 1 < nk) {
            stage((t + 1) << 6, (t + 1) & 1);
            asm volatile("s_waitcnt vmcnt(8)" ::: "memory");
        } else {
            asm volatile("s_waitcnt vmcnt(0)" ::: "memory");
        }
        __builtin_amdgcn_s_barrier();

        #pragma unroll
        for (int kk = 0; kk < 2; ++kk) {
            const int sc = kk * 4 + lq;
            short8 a[4], b[4];
            #pragma unroll
            for (int mi = 0; mi < 4; ++mi) {
                int row = wr * 64 + mi * 16 + l15;
                a[mi] = *reinterpret_cast<const short8*>(As + row * 128 + ((sc ^ (row & 7)) << 4));
            }
            #pragma unroll
            for (int ni = 0; ni < 4; ++ni) {
                int row = wc * 64 + ni * 16 + l15;
                b[ni] = *reinterpret_cast<const short8*>(Bs + row * 128 + ((sc ^ (row & 7)) << 4));
            }
            #pragma unroll
            for (int mi = 0; mi < 4; ++mi)
                #pragma unroll
                for (int ni = 0; ni < 4; ++ni)
                    acc[mi][ni] = __builtin_amdgcn_mfma_f32_16x16x32_bf16(a[mi], b[ni], acc[mi][ni], 0, 0, 0);
        }

        asm volatile("" ::: "memory");
        __builtin_amdgcn_s_barrier();
    }

    #pragma unroll
    for (int mi = 0; mi < 4; ++mi) {
        #pragma unroll
        for (int ni = 0; ni < 4; ++ni) {
            int col = n0 + wc * 64 + ni * 16 + l15;
            float bv = BIAS ? bias[col] : 0.0f;
            #pragma unroll
            for (int r = 0; r < 4; ++r) {
                int row = m0 + wr * 64 + mi * 16 + lq * 4 + r;
                float v = acc[mi][ni][r] + bv;
                if (RELU) v = v > 0.0f ? v : 0.0f;
                if (RESID) v += resid[(size_t)row * ldo + col];
                if (OUTB) ((u16*)out)[(size_t)row * ldo + col] = f2b(v);
                else      ((float*)out)[(size_t)row * ldo + col] = v;
            }
        }
    }
}

// ---------- FF2 split-K GEMM: grid (8, 32, 2), 2 blocks/CU ----------
// z=0: K in [0,2048)   -> out = acc + b2 + yF   (f32, d_out)
// z=1: K in [2048,4096)-> p1  = acc             (f32 partial)
// add_kernel then does out += p1.
__global__ __launch_bounds__(256) void gemm_ff2(
    const u16* __restrict__ A,      // hbuf [4096,4096]
    const u16* __restrict__ BT,     // w2T  [1024,4096]
    float* __restrict__ outp,
    float* __restrict__ p1,
    const float* __restrict__ bias,
    const float* __restrict__ resid)
{
    __shared__ __align__(16) char smem[64 * 1024];
    const int tid = threadIdx.x;
    const int lane = tid & 63, w = tid >> 6;
    const int wr = w >> 1, wc = w & 1;
    const int l15 = lane & 15, lq = lane >> 4;
    const int z = blockIdx.z;
    const int koff = z * 2048;

    const int nx = gridDim.x;           // 8
    const int nwg = nx * gridDim.y;     // 256
    int orig = blockIdx.y * nx + blockIdx.x;
    int wgid = (orig & 7) * (nwg >> 3) + (orig >> 3);
    const int m0 = (wgid / nx) * 128, n0 = (wgid % nx) * 128;

    auto stage = [&](int kt, int buf) {
        char* As = smem + buf * 32768;
        char* Bs = smem + buf * 32768 + 16384;
        #pragma unroll
        for (int it = 0; it < 4; ++it) {
            int slot = it * 256 + tid;
            int row = slot >> 3, c8 = (slot & 7) ^ (row & 7);
            gll16(A + (size_t)(m0 + row) * 4096 + koff + kt + c8 * 8, As + (it * 256 + w * 64) * 16);
        }
        #pragma unroll
        for (int it = 0; it < 4; ++it) {
            int slot = it * 256 + tid;
            int row = slot >> 3, c8 = (slot & 7) ^ (row & 7);
            gll16(BT + (size_t)(n0 + row) * 4096 + koff + kt + c8 * 8, Bs + (it * 256 + w * 64) * 16);
        }
    };

    f32x4 acc[4][4] = {};
    const int nk = 32;                  // 2048 / 64

    stage(0, 0);
    asm volatile("s_waitcnt vmcnt(0)" ::: "memory");
    __builtin_amdgcn_s_barrier();

    for (int t = 0; t < nk; ++t) {
        const char* As = smem + (t & 1) * 32768;
        const char* Bs = smem + (t & 1) * 32768 + 16384;
        if (t + 1 < nk) {
            stage((t + 1) << 6, (t + 1) & 1);
            asm volatile("s_waitcnt vmcnt(8)" ::: "memory");
        } else {
            asm volatile("s_waitcnt vmcnt(0)" ::: "memory");
        }
        __builtin_amdgcn_s_barrier();

        #pragma unroll
        for (int kk = 0; kk < 2; ++kk) {
            const int sc = kk * 4 + lq;
            short8 a[4], b[4];
            #pragma unroll
            for (int mi = 0; mi < 4; ++mi) {
                int row = wr * 64 + mi * 16 + l15;
                a[mi] = *reinterpret_cast<const short8*>(As + row * 128 + ((sc ^ (row & 7)) << 4));
            }
            #pragma unroll
            for (int ni = 0; ni < 4; ++ni) {
                int row = wc * 64 + ni * 16 + l15;
                b[ni] = *reinterpret_cast<const short8*>(Bs + row * 128 + ((sc ^ (row & 7)) << 4));
            }
            #pragma unroll
            for (int mi = 0; mi < 4; ++mi)
                #pragma unroll
                for (int ni = 0; ni < 4; ++ni)
                    acc[mi][ni] = __builtin_amdgcn_mfma_f32_16x16x32_bf16(a[mi], b[ni], acc[mi][ni], 0, 0, 0);
        }

        asm volatile("" ::: "memory");
        __builtin_amdgcn_s_barrier();
    }

    #pragma unroll
    for (int mi = 0; mi < 4; ++mi) {
        #pragma unroll
        for (int ni = 0; ni < 4; ++ni) {
            int col = n0 + wc * 64 + ni * 16 + l15;
            #pragma unroll
            for (int r = 0; r < 4; ++r) {
                int row = m0 + wr * 64 + mi * 16 + lq * 4 + r;
                float v = acc[mi][ni][r];
                if (z == 0) {
                    v += bias[col] + resid[(size_t)row * 1024 + col];
                    outp[(size_t)row * 1024 + col] = v;
                } else {
                    p1[(size_t)row * 1024 + col] = v;
                }
            }
        }
    }
}

// out += p1  (f32, vectorized, grid-stride)
__global__ __launch_bounds__(256) void add_kernel(
    float* __restrict__ out, const float* __restrict__ p1, int n4)
{
    int i = blockIdx.x * 256 + threadIdx.x;
    int stride = gridDim.x * 256;
    for (; i < n4; i += stride) {
        float4 a = reinterpret_cast<float4*>(out)[i];
        float4 b = reinterpret_cast<const float4*>(p1)[i];
        a.x += b.x; a.y += b.y; a.z += b.z; a.w += b.w;
        reinterpret_cast<float4*>(out)[i] = a;
    }
}

// ---------- GEMM 256x256, 8 waves, dbuf + counted vmcnt (T4) ----------
template<bool BIAS, bool RELU, bool OUTB>
__global__ __launch_bounds__(512) void gemm_bt256(
    const u16* __restrict__ A, int lda,
    const u16* __restrict__ BT, int ldb,
    void* __restrict__ out, int ldo,
    const float* __restrict__ bias,
    int K)
{
    __shared__ __align__(16) char smem[128 * 1024];
    const int tid = threadIdx.x;
    const int lane = tid & 63, wid = tid >> 6;
    const int wm = wid >> 2, wn = wid & 3;
    const int l15 = lane & 15, lq = lane >> 4;

    const int nx = gridDim.x;
    const int nwg = nx * gridDim.y;
    int orig = blockIdx.y * nx + blockIdx.x;
    int wgid = orig;
    if ((nwg & 7) == 0) wgid = (orig & 7) * (nwg >> 3) + (orig >> 3);
    const int m0 = (wgid / nx) * 256, n0 = (wgid % nx) * 256;

    auto stage = [&](int kt, int buf) {
        char* As = smem + buf * 65536;
        char* Bs = smem + buf * 65536 + 32768;
        #pragma unroll
        for (int i = 0; i < 4; ++i) {
            int slot = i * 512 + tid;
            int row = slot >> 3, c8 = (slot & 7) ^ (row & 7);
            gll16(A + (size_t)(m0 + row) * lda + kt + c8 * 8, As + (i * 512 + wid * 64) * 16);
        }
        #pragma unroll
        for (int i = 0; i < 4; ++i) {
            int slot = i * 512 + tid;
            int row = slot >> 3, c8 = (slot & 7) ^ (row & 7);
            gll16(BT + (size_t)(n0 + row) * ldb + kt + c8 * 8, Bs + (i * 512 + wid * 64) * 16);
        }
    };

    f32x4 acc[8][4] = {};
    const int nk = K >> 6;

    stage(0, 0);
    asm volatile("s_waitcnt vmcnt(0)" ::: "memory");
    __builtin_amdgcn_s_barrier();

    for (int t = 0; t < nk; ++t) {
        const char* As = smem + (t & 1) * 65536;
        const char* Bs = smem + (t & 1) * 65536 + 32768;
        if (t + 1 < nk) {
            stage((t + 1) << 6, (t + 1) & 1);
            asm volatile("s_waitcnt vmcnt(8)" ::: "memory");
        } else {
            asm volatile("s_waitcnt vmcnt(0)" ::: "memory");
        }
        __builtin_amdgcn_s_barrier();

        #pragma unroll
        for (int kk = 0; kk < 2; ++kk) {
            const int sc = kk * 4 + lq;
            short8 a[8], b[4];
            #pragma unroll
            for (int mi = 0; mi < 8; ++mi) {
                int row = wm * 128 + mi * 16 + l15;
                a[mi] = *reinterpret_cast<const short8*>(As + row * 128 + ((sc ^ (row & 7)) << 4));
            }
            #pragma unroll
            for (int ni = 0; ni < 4; ++ni) {
                int row = wn * 64 + ni * 16 + l15;
                b[ni] = *reinterpret_cast<const short8*>(Bs + row * 128 + ((sc ^ (row & 7)) << 4));
            }
            #pragma unroll
            for (int mi = 0; mi < 8; ++mi)
                #pragma unroll
                for (int ni = 0; ni < 4; ++ni)
                    acc[mi][ni] = __builtin_amdgcn_mfma_f32_16x16x32_bf16(a[mi], b[ni], acc[mi][ni], 0, 0, 0);
        }

        asm volatile("" ::: "memory");
        __builtin_amdgcn_s_barrier();
    }

    #pragma unroll
    for (int mi = 0; mi < 8; ++mi) {
        #pragma unroll
        for (int ni = 0; ni < 4; ++ni) {
            int col = n0 + wn * 64 + ni * 16 + l15;
            float bv = BIAS ? bias[col] : 0.0f;
            #pragma unroll
            for (int r = 0; r < 4; ++r) {
                int row = m0 + wm * 128 + mi * 16 + lq * 4 + r;
                float v = acc[mi][ni][r] + bv;
                if (RELU) v = v > 0.0f ? v : 0.0f;
                if (OUTB) ((u16*)out)[(size_t)row * ldo + col] = f2b(v);
                else      ((float*)out)[(size_t)row * ldo + col] = v;
            }
        }
    }
}

// ---------- flash attention ----------
// Grid (32 bh, 16): qbi = by<8 ? 15-by : by-8 -> blocks c and c+256 are
// complementary; under round-robin dispatch each CU hosts 36 KV-tiles total
// with 2 blocks (8 waves) co-resident for VALU/MFMA overlap.
__global__ __launch_bounds__(256, 2) void attn_kernel(
    const u16* __restrict__ qkv, const u16* __restrict__ vt, u16* __restrict__ att)
{
    __shared__ __align__(16) char smem[48 * 1024];
    char* Kb0 = smem;
    char* Kb1 = smem + 8192;
    char* Vb0 = smem + 16384;
    char* Vb1 = smem + 24576;
    char* Ost = smem + 32768;

    const int tid = threadIdx.x, lane = tid & 63, w = tid >> 6;
    const int l31 = lane & 31, hi = lane >> 5;
    const int bh = blockIdx.x;
    const int by = blockIdx.y;
    const int qbi = (by < 8) ? (15 - by) : (by - 8);
    const int b = bh >> 4, h = bh & 15;
    const size_t base = (size_t)b * 2048;
    const int kcol = 1024 + h * 64;
    const u16* vtp = vt + (size_t)bh * 64 * 2048;
    const float SC = 0.03125f * 1.44269504f;   // C^-0.5 * log2(e)

    const int q0w = qbi * 128 + w * 32;
    const int nst = 2 * qbi + 2;
    const int qg = q0w + l31;

    auto stage = [&](int st, char* kb, char* vb) {
        #pragma unroll
        for (int i = 0; i < 2; ++i) {
            int seg = w * 2 + i;
            int slot = seg * 64 + lane;
            int s = slot >> 3, d8p = slot & 7;
            gll16(qkv + (base + st * 64 + s) * 3072 + kcol + ((d8p ^ (s & 7)) * 8),
                  kb + seg * 1024);
            int d = s, s8p = d8p;
            gll16(vtp + (size_t)d * 2048 + st * 64 + ((s8p ^ (d & 7)) * 8),
                  vb + seg * 1024);
        }
    };

    // Q B-frags, pre-scaled by SC
    short8 qf[4];
    {
        const u16* qp = qkv + (base + q0w + l31) * 3072 + h * 64 + hi * 8;
        #pragma unroll
        for (int dc = 0; dc < 4; ++dc) {
            short8 q = *reinterpret_cast<const short8*>(qp + dc * 16);
            #pragma unroll
            for (int j = 0; j < 8; j += 2) {
                u32 pk = cvtpk(b2f((u16)q[j]) * SC, b2f((u16)q[j + 1]) * SC);
                q[j]     = (short)(pk & 0xffff);
                q[j + 1] = (short)(pk >> 16);
            }
            qf[dc] = q;
        }
    }

    f32x16 oT[2] = {};
    float m = -1e30f, lsum = 0.0f;

    stage(0, Kb0, Vb0);
    __syncthreads();

    for (int st = 0; st < nst; ++st) {
        char* kb = (st & 1) ? Kb1 : Kb0;
        char* vb = (st & 1) ? Vb1 : Vb0;
        if (st + 1 < nst) stage(st + 1, (st & 1) ? Kb0 : Kb1, (st & 1) ? Vb0 : Vb1);

        f32x16 sa[2] = {};
        #pragma unroll
        for (int dc = 0; dc < 4; ++dc) {
            #pragma unroll
            for (int sb = 0; sb < 2; ++sb) {
                int s = sb * 32 + l31;
                int slot = (dc * 2 + hi) ^ (s & 7);
                short8 kf = *reinterpret_cast<const short8*>(kb + s * 128 + slot * 16);
                sa[sb] = __builtin_amdgcn_mfma_f32_32x32x16_bf16(kf, qf[dc], sa[sb], 0, 0, 0);
            }
        }

        if (st >= nst - 2) {
            #pragma unroll
            for (int sb = 0; sb < 2; ++sb)
                #pragma unroll
                for (int r = 0; r < 16; ++r) {
                    int sg = st * 64 + sb * 32 + (r & 3) + 8 * (r >> 2) + 4 * hi;
                    if (sg > qg) sa[sb][r] = -1e30f;
                }
        }

        float t8[8];
        #pragma unroll
        for (int i = 0; i < 8; ++i)
            t8[i] = fmaxf(fmaxf(sa[0][i], sa[0][i + 8]), fmaxf(sa[1][i], sa[1][i + 8]));
        float t4a = fmaxf(t8[0], t8[4]), t4b = fmaxf(t8[1], t8[5]);
        float t4c = fmaxf(t8[2], t8[6]), t4d = fmaxf(t8[3], t8[7]);
        float mx = fmaxf(fmaxf(t4a, t4b), fmaxf(t4c, t4d));
        mx = fmaxf(mx, __shfl_xor(mx, 32));

        if (!__all(mx <= m + 8.0f)) {
            float nm = fmaxf(m, mx);
            float sf = ex2(m - nm);
            m = nm;
            lsum *= sf;
            #pragma unroll
            for (int dt = 0; dt < 2; ++dt)
                #pragma unroll
                for (int r = 0; r < 16; ++r) oT[dt][r] *= sf;
        }

        #pragma unroll
        for (int sb = 0; sb < 2; ++sb)
            #pragma unroll
            for (int r = 0; r < 16; ++r) sa[sb][r] = ex2(sa[sb][r] - m);
        float s8_[8];
        #pragma unroll
        for (int i = 0; i < 8; ++i)
            s8_[i] = (sa[0][i] + sa[0][i + 8]) + (sa[1][i] + sa[1][i + 8]);
        float s4a = s8_[0] + s8_[4], s4b = s8_[1] + s8_[5];
        float s4c = s8_[2] + s8_[6], s4d = s8_[3] + s8_[7];
        float ps = (s4a + s4b) + (s4c + s4d);
        ps += __shfl_xor(ps, 32);
        lsum += ps;

        u32 pkE[4][2], pkO[4][2];
        #pragma unroll
        for (int sc = 0; sc < 4; ++sc) {
            const int sb = sc >> 1, rb = 8 * (sc & 1);
            #pragma unroll
            for (int c = 0; c < 2; ++c) {
                pkE[sc][c] = cvtpk(sa[sb][rb + 2 * c], sa[sb][rb + 2 * c + 1]);
                pkO[sc][c] = cvtpk(sa[sb][rb + 4 + 2 * c], sa[sb][rb + 4 + 2 * c + 1]);
            }
        }

        #pragma unroll
        for (int sc = 0; sc < 4; ++sc) {
            u32 wd[4];
            #pragma unroll
            for (int ww = 0; ww < 4; ++ww) {
                const int c = ww & 1;
                u32 own  = hi ? pkO[sc][c] : pkE[sc][c];
                u32 send = hi ? pkE[sc][c] : pkO[sc][c];
                u32 ex = (u32)__shfl_xor((int)send, 32);
                wd[ww] = ((ww >> 1) == hi) ? own : ex;
            }
            union { u32 u[4]; short8 s8; } pb_;
            pb_.u[0] = wd[0]; pb_.u[1] = wd[1]; pb_.u[2] = wd[2]; pb_.u[3] = wd[3];
            #pragma unroll
            for (int dt = 0; dt < 2; ++dt) {
                int d = dt * 32 + l31;
                int slot = (sc * 2 + hi) ^ (d & 7);
                short8 vf = *reinterpret_cast<const short8*>(vb + d * 128 + slot * 16);
                oT[dt] = __builtin_amdgcn_mfma_f32_32x32x16_bf16(vf, pb_.s8, oT[dt], 0, 0, 0);
            }
        }
        __syncthreads();
    }

    // epilogue: O^T -> per-wave LDS transpose -> coalesced store
    {
        float inv = 1.0f / lsum;
        char* ob = Ost + w * 4096;
        #pragma unroll
        for (int dt = 0; dt < 2; ++dt)
            #pragma unroll
            for (int rp = 0; rp < 8; ++rp) {
                int r = rp * 2;
                int d = dt * 32 + (r & 3) + 8 * (r >> 2) + 4 * hi;
                u32 pk2 = cvtpk(oT[dt][r] * inv, oT[dt][r + 1] * inv);
                int byte = l31 * 128 + ((((d >> 3) ^ (l31 & 7)) << 4)) + (d & 7) * 2;
                *reinterpret_cast<u32*>(ob + byte) = pk2;
            }
        int q = lane >> 1, half = lane & 1;
        size_t grow = (base + q0w + q) * 1024 + h * 64 + half * 32;
        #pragma unroll
        for (int c = 0; c < 4; ++c) {
            int chunk = half * 4 + c;
            int byte = q * 128 + ((chunk ^ (q & 7)) << 4);
            float4 vv = *reinterpret_cast<const float4*>(ob + byte);
            *reinterpret_cast<float4*>(att + grow + c * 8) = vv;
        }
    }
}

// ---------- launch ----------
extern "C" void kernel_launch(void* const* d_in, const int* in_sizes, int n_in,
                              void* d_out, int out_size, void* d_ws, size_t ws_size,
                              hipStream_t stream)
{
    const float* x   = (const float*)d_in[0];
    const float* Wq  = (const float*)d_in[1];
    const float* Wk  = (const float*)d_in[2];
    const float* Wv  = (const float*)d_in[3];
    const float* Wp  = (const float*)d_in[4];
    const float* bp  = (const float*)d_in[5];
    const float* W1  = (const float*)d_in[6];
    const float* b1  = (const float*)d_in[7];
    const float* W2  = (const float*)d_in[8];
    const float* b2  = (const float*)d_in[9];
    const float* g1  = (const float*)d_in[10];
    const float* be1 = (const float*)d_in[11];
    const float* g2  = (const float*)d_in[12];
    const float* be2 = (const float*)d_in[13];
    float* out = (float*)d_out;

    char* ws = (char*)d_ws;
    u16*   wqkvT = (u16*)(ws + 0);                  //  6 MiB [3072,1024]
    u16*   wpT   = (u16*)(ws + 6291456);            //  2 MiB [1024,1024]
    u16*   w1T   = (u16*)(ws + 8388608);            //  8 MiB [4096,1024]
    u16*   w2T   = (u16*)(ws + 16777216);           //  8 MiB [1024,4096]
    float* xlnF  = (float*)(ws + 25165824);         // 16 MiB (dead after proj -> reused as p1)
    float* p1f   = (float*)(ws + 25165824);         // 16 MiB f32 partial for FF2 split-K
    u16*   xlnB  = (u16*)(ws + 41943040);           //  8 MiB (also yB)
    u16*   qkv   = (u16*)(ws + 50331648);           // 24 MiB
    float* x2    = (float*)(ws + 50331648);         // reuse after attn
    u16*   hbuf  = (u16*)(ws + 50331648);           // reuse after ln2
    u16*   attb  = (u16*)(ws + 75497472);           //  8 MiB
    float* yF    = (float*)(ws + 83886080);         // 16 MiB (after attn)
    u16*   vtb   = (u16*)(ws + 83886080);           //  8 MiB (before ln2)
    u16*   yB    = xlnB;

    repack_qkv_tiled<<<dim3(16, 48), 256, 0, stream>>>(Wq, Wk, Wv, wqkvT);
    trans_tiled<<<dim3(16, 16), 256, 0, stream>>>(Wp, wpT, 1024, 1024);
    trans_tiled<<<dim3(16, 64), 256, 0, stream>>>(W1, w1T, 1024, 4096);
    trans_tiled<<<dim3(64, 16), 256, 0, stream>>>(W2, w2T, 4096, 1024);

    ln_kernel<<<4096, 256, 0, stream>>>(x, g1, be1, xlnF, xlnB);

    // QKV = xln @ Wqkv -> bf16 [4096, 3072]   (256^2, 192 blocks)
    gemm_bt256<false, false, true><<<dim3(12, 16), 512, 0, stream>>>(
        xlnB, 1024, wqkvT, 1024, qkv, 3072, nullptr, 1024);

    vt_kernel<<<dim3(32, 16, 2), 256, 0, stream>>>(qkv, vtb);
    attn_kernel<<<dim3(32, 16), 256, 0, stream>>>(qkv, vtb, attb);

    gemm_bt<true, false, true, false><<<dim3(8, 32), 256, 0, stream>>>(
        attb, 1024, wpT, 1024, x2, 1024, bp, xlnF, 1024);

    ln_kernel<<<4096, 256, 0, stream>>>(x2, g2, be2, yF, yB);

    // FF1 = relu(y @ W1 + b1) -> bf16 [4096, 4096]   (256^2, 256 blocks)
    gemm_bt256<true, true, true><<<dim3(16, 16), 512, 0, stream>>>(
        yB, 1024, w1T, 1024, hbuf, 4096, b1, 1024);

    // FF2 split-K: z=0 -> out = h[:, :2048] @ W2[:2048] + b2 + yF
    //              z=1 -> p1  = h[:, 2048:] @ W2[2048:]
    gemm_ff2<<<dim3(8, 32, 2), 256, 0, stream>>>(hbuf, w2T, out, p1f, b2, yF);
    add_kernel<<<2048, 256, 0, stream>>>(out, p1f, 1048576);
}

// Round 14
// 221.308 us; speedup vs baseline: 1.0765x; 1.0765x over previous
//
#include <hip/hip_runtime.h>
#include <hip/hip_bf16.h>
#include <cstdint>
#include <cstddef>

typedef __attribute__((ext_vector_type(8))) short short8;
typedef __attribute__((ext_vector_type(4))) float f32x4;
typedef __attribute__((ext_vector_type(16))) float f32x16;
typedef unsigned int u32;
typedef unsigned short u16;

// ---------- helpers ----------
__device__ inline u16 f2b(float x) {
    union { float f; u32 u; } v; v.f = x;
    u32 u = v.u;
    u32 r = (u + 0x7fff + ((u >> 16) & 1)) >> 16;
    return (u16)r;
}
__device__ inline float b2f(u16 h) {
    union { u32 u; float f; } v; v.u = ((u32)h) << 16;
    return v.f;
}
__device__ inline u32 cvtpk(float lo, float hi) {
    u32 r; asm("v_cvt_pk_bf16_f32 %0, %1, %2" : "=v"(r) : "v"(lo), "v"(hi)); return r;
}
__device__ inline float ex2(float x) {   // raw v_exp_f32: D = 2^S0
    float r; asm("v_exp_f32 %0, %1" : "=v"(r) : "v"(x)); return r;
}
__device__ inline void gll16(const void* g, void* l) {
    __builtin_amdgcn_global_load_lds(
        (const __attribute__((address_space(1))) void*)g,
        (__attribute__((address_space(3))) void*)l, 16, 0, 0);
}

// ---------- tiled weight repacks ----------
__global__ __launch_bounds__(256) void repack_qkv_tiled(
    const float* __restrict__ Wq, const float* __restrict__ Wk, const float* __restrict__ Wv,
    u16* __restrict__ out)
{
    __shared__ u16 lds[64 * 72];
    const int tid = threadIdx.x;
    const int c0 = blockIdx.x * 64;
    const int sh = blockIdx.y;
    const int sel = sh >> 4, h = sh & 15;
    const float* W = (sel == 0) ? Wq : (sel == 1) ? Wk : Wv;
    #pragma unroll
    for (int it = 0; it < 4; ++it) {
        int idx = tid + it * 256;
        int c = idx >> 4, d4 = idx & 15;
        float4 v = *reinterpret_cast<const float4*>(&W[((size_t)(h * 1024 + c0 + c)) * 64 + d4 * 4]);
        lds[(d4 * 4 + 0) * 72 + c] = f2b(v.x);
        lds[(d4 * 4 + 1) * 72 + c] = f2b(v.y);
        lds[(d4 * 4 + 2) * 72 + c] = f2b(v.z);
        lds[(d4 * 4 + 3) * 72 + c] = f2b(v.w);
    }
    __syncthreads();
    #pragma unroll
    for (int it = 0; it < 2; ++it) {
        int idx = tid + it * 256;
        int d = idx >> 3, c8 = idx & 7;
        short8 s = *reinterpret_cast<const short8*>(&lds[d * 72 + c8 * 8]);
        *reinterpret_cast<short8*>(&out[((size_t)(sel * 1024 + h * 64 + d)) * 1024 + c0 + c8 * 8]) = s;
    }
}

__global__ __launch_bounds__(256) void trans_tiled(
    const float* __restrict__ in, u16* __restrict__ out, int P, int Q)
{
    __shared__ u16 lds[64 * 72];
    const int tid = threadIdx.x;
    const int p0 = blockIdx.x * 64, q0 = blockIdx.y * 64;
    #pragma unroll
    for (int it = 0; it < 4; ++it) {
        int idx = tid + it * 256;
        int p = idx >> 4, q4 = idx & 15;
        float4 v = *reinterpret_cast<const float4*>(&in[(size_t)(p0 + p) * Q + q0 + q4 * 4]);
        lds[(q4 * 4 + 0) * 72 + p] = f2b(v.x);
        lds[(q4 * 4 + 1) * 72 + p] = f2b(v.y);
        lds[(q4 * 4 + 2) * 72 + p] = f2b(v.z);
        lds[(q4 * 4 + 3) * 72 + p] = f2b(v.w);
    }
    __syncthreads();
    #pragma unroll
    for (int it = 0; it < 2; ++it) {
        int idx = tid + it * 256;
        int q = idx >> 3, p8 = idx & 7;
        short8 s = *reinterpret_cast<const short8*>(&lds[q * 72 + p8 * 8]);
        *reinterpret_cast<short8*>(&out[(size_t)(q0 + q) * P + p0 + p8 * 8]) = s;
    }
}

// Vt[b][h][d=64][s=2048] bf16 from qkv V region
__global__ __launch_bounds__(256) void vt_kernel(
    const u16* __restrict__ qkv, u16* __restrict__ vt)
{
    __shared__ u16 lds[64 * 72];
    const int tid = threadIdx.x;
    const int s0 = blockIdx.x * 64, h = blockIdx.y, b = blockIdx.z;
    #pragma unroll
    for (int it = 0; it < 2; ++it) {
        int idx = tid + it * 256;
        int s = idx >> 3, d8 = idx & 7;
        short8 kv = *reinterpret_cast<const short8*>(
            &qkv[((size_t)(b * 2048 + s0 + s)) * 3072 + 2048 + h * 64 + d8 * 8]);
        #pragma unroll
        for (int j = 0; j < 8; ++j) lds[(d8 * 8 + j) * 72 + s] = (u16)kv[j];
    }
    __syncthreads();
    #pragma unroll
    for (int it = 0; it < 2; ++it) {
        int idx = tid + it * 256;
        int d = idx >> 3, s8 = idx & 7;
        short8 s = *reinterpret_cast<const short8*>(&lds[d * 72 + s8 * 8]);
        *reinterpret_cast<short8*>(&vt[((size_t)(b * 16 + h) * 64 + d) * 2048 + s0 + s8 * 8]) = s;
    }
}

// ---------- layernorm ----------
__global__ __launch_bounds__(256) void ln_kernel(
    const float* __restrict__ x, const float* __restrict__ g, const float* __restrict__ be,
    float* __restrict__ yf, u16* __restrict__ yb)
{
    int row = blockIdx.x;
    const float4 v = reinterpret_cast<const float4*>(x + (size_t)row * 1024)[threadIdx.x];
    float s  = v.x + v.y + v.z + v.w;
    float s2 = v.x * v.x + v.y * v.y + v.z * v.z + v.w * v.w;
    #pragma unroll
    for (int o = 32; o >= 1; o >>= 1) { s += __shfl_xor(s, o); s2 += __shfl_xor(s2, o); }
    __shared__ float red[8];
    int w = threadIdx.x >> 6;
    if ((threadIdx.x & 63) == 0) { red[w] = s; red[4 + w] = s2; }
    __syncthreads();
    s  = red[0] + red[1] + red[2] + red[3];
    s2 = red[4] + red[5] + red[6] + red[7];
    float mu = s * (1.0f / 1024.0f);
    float var = s2 * (1.0f / 1024.0f) - mu * mu;
    float rs = rsqrtf(var + 1e-5f);
    const float4 gg = reinterpret_cast<const float4*>(g)[threadIdx.x];
    const float4 bb = reinterpret_cast<const float4*>(be)[threadIdx.x];
    float4 o;
    o.x = (v.x - mu) * rs * gg.x + bb.x;
    o.y = (v.y - mu) * rs * gg.y + bb.y;
    o.z = (v.z - mu) * rs * gg.z + bb.z;
    o.w = (v.w - mu) * rs * gg.w + bb.w;
    reinterpret_cast<float4*>(yf + (size_t)row * 1024)[threadIdx.x] = o;
    uint2 pk;
    pk.x = (u32)f2b(o.x) | ((u32)f2b(o.y) << 16);
    pk.y = (u32)f2b(o.z) | ((u32)f2b(o.w) << 16);
    reinterpret_cast<uint2*>(yb + (size_t)row * 1024)[threadIdx.x] = pk;
}

// ---------- GEMM 128x128, dbuf + counted vmcnt(8) ----------
template<bool BIAS, bool RELU, bool RESID, bool OUTB>
__global__ __launch_bounds__(256) void gemm_bt(
    const u16* __restrict__ A, int lda,
    const u16* __restrict__ BT, int ldb,
    void* __restrict__ out, int ldo,
    const float* __restrict__ bias,
    const float* __restrict__ resid,
    int K)
{
    __shared__ __align__(16) char smem[64 * 1024];
    const int tid = threadIdx.x;
    const int lane = tid & 63, w = tid >> 6;
    const int wr = w >> 1, wc = w & 1;
    const int l15 = lane & 15, lq = lane >> 4;

    const int nx = gridDim.x;
    const int nwg = nx * gridDim.y;
    int orig = blockIdx.y * nx + blockIdx.x;
    int wgid = orig;
    if ((nwg & 7) == 0) wgid = (orig & 7) * (nwg >> 3) + (orig >> 3);
    const int m0 = (wgid / nx) * 128, n0 = (wgid % nx) * 128;

    auto stage = [&](int kt, int buf) {
        char* As = smem + buf * 32768;
        char* Bs = smem + buf * 32768 + 16384;
        #pragma unroll
        for (int it = 0; it < 4; ++it) {
            int slot = it * 256 + tid;
            int row = slot >> 3, c8 = (slot & 7) ^ (row & 7);
            gll16(A + (size_t)(m0 + row) * lda + kt + c8 * 8, As + (it * 256 + w * 64) * 16);
        }
        #pragma unroll
        for (int it = 0; it < 4; ++it) {
            int slot = it * 256 + tid;
            int row = slot >> 3, c8 = (slot & 7) ^ (row & 7);
            gll16(BT + (size_t)(n0 + row) * ldb + kt + c8 * 8, Bs + (it * 256 + w * 64) * 16);
        }
    };

    f32x4 acc[4][4] = {};
    const int nk = K >> 6;

    stage(0, 0);
    asm volatile("s_waitcnt vmcnt(0)" ::: "memory");
    __builtin_amdgcn_s_barrier();

    for (int t = 0; t < nk; ++t) {
        const char* As = smem + (t & 1) * 32768;
        const char* Bs = smem + (t & 1) * 32768 + 16384;
        if (t + 1 < nk) {
            stage((t + 1) << 6, (t + 1) & 1);
            asm volatile("s_waitcnt vmcnt(8)" ::: "memory");
        } else {
            asm volatile("s_waitcnt vmcnt(0)" ::: "memory");
        }
        __builtin_amdgcn_s_barrier();

        #pragma unroll
        for (int kk = 0; kk < 2; ++kk) {
            const int sc = kk * 4 + lq;
            short8 a[4], b[4];
            #pragma unroll
            for (int mi = 0; mi < 4; ++mi) {
                int row = wr * 64 + mi * 16 + l15;
                a[mi] = *reinterpret_cast<const short8*>(As + row * 128 + ((sc ^ (row & 7)) << 4));
            }
            #pragma unroll
            for (int ni = 0; ni < 4; ++ni) {
                int row = wc * 64 + ni * 16 + l15;
                b[ni] = *reinterpret_cast<const short8*>(Bs + row * 128 + ((sc ^ (row & 7)) << 4));
            }
            #pragma unroll
            for (int mi = 0; mi < 4; ++mi)
                #pragma unroll
                for (int ni = 0; ni < 4; ++ni)
                    acc[mi][ni] = __builtin_amdgcn_mfma_f32_16x16x32_bf16(a[mi], b[ni], acc[mi][ni], 0, 0, 0);
        }

        asm volatile("" ::: "memory");
        __builtin_amdgcn_s_barrier();
    }

    #pragma unroll
    for (int mi = 0; mi < 4; ++mi) {
        #pragma unroll
        for (int ni = 0; ni < 4; ++ni) {
            int col = n0 + wc * 64 + ni * 16 + l15;
            float bv = BIAS ? bias[col] : 0.0f;
            #pragma unroll
            for (int r = 0; r < 4; ++r) {
                int row = m0 + wr * 64 + mi * 16 + lq * 4 + r;
                float v = acc[mi][ni][r] + bv;
                if (RELU) v = v > 0.0f ? v : 0.0f;
                if (RESID) v += resid[(size_t)row * ldo + col];
                if (OUTB) ((u16*)out)[(size_t)row * ldo + col] = f2b(v);
                else      ((float*)out)[(size_t)row * ldo + col] = v;
            }
        }
    }
}

// ---------- GEMM 256x256, 8 waves, dbuf + counted vmcnt (T4) ----------
template<bool BIAS, bool RELU, bool OUTB>
__global__ __launch_bounds__(512) void gemm_bt256(
    const u16* __restrict__ A, int lda,
    const u16* __restrict__ BT, int ldb,
    void* __restrict__ out, int ldo,
    const float* __restrict__ bias,
    int K)
{
    __shared__ __align__(16) char smem[128 * 1024];
    const int tid = threadIdx.x;
    const int lane = tid & 63, wid = tid >> 6;
    const int wm = wid >> 2, wn = wid & 3;
    const int l15 = lane & 15, lq = lane >> 4;

    const int nx = gridDim.x;
    const int nwg = nx * gridDim.y;
    int orig = blockIdx.y * nx + blockIdx.x;
    int wgid = orig;
    if ((nwg & 7) == 0) wgid = (orig & 7) * (nwg >> 3) + (orig >> 3);
    const int m0 = (wgid / nx) * 256, n0 = (wgid % nx) * 256;

    auto stage = [&](int kt, int buf) {
        char* As = smem + buf * 65536;
        char* Bs = smem + buf * 65536 + 32768;
        #pragma unroll
        for (int i = 0; i < 4; ++i) {
            int slot = i * 512 + tid;
            int row = slot >> 3, c8 = (slot & 7) ^ (row & 7);
            gll16(A + (size_t)(m0 + row) * lda + kt + c8 * 8, As + (i * 512 + wid * 64) * 16);
        }
        #pragma unroll
        for (int i = 0; i < 4; ++i) {
            int slot = i * 512 + tid;
            int row = slot >> 3, c8 = (slot & 7) ^ (row & 7);
            gll16(BT + (size_t)(n0 + row) * ldb + kt + c8 * 8, Bs + (i * 512 + wid * 64) * 16);
        }
    };

    f32x4 acc[8][4] = {};
    const int nk = K >> 6;

    stage(0, 0);
    asm volatile("s_waitcnt vmcnt(0)" ::: "memory");
    __builtin_amdgcn_s_barrier();

    for (int t = 0; t < nk; ++t) {
        const char* As = smem + (t & 1) * 65536;
        const char* Bs = smem + (t & 1) * 65536 + 32768;
        if (t + 1 < nk) {
            stage((t + 1) << 6, (t + 1) & 1);
            asm volatile("s_waitcnt vmcnt(8)" ::: "memory");
        } else {
            asm volatile("s_waitcnt vmcnt(0)" ::: "memory");
        }
        __builtin_amdgcn_s_barrier();

        #pragma unroll
        for (int kk = 0; kk < 2; ++kk) {
            const int sc = kk * 4 + lq;
            short8 a[8], b[4];
            #pragma unroll
            for (int mi = 0; mi < 8; ++mi) {
                int row = wm * 128 + mi * 16 + l15;
                a[mi] = *reinterpret_cast<const short8*>(As + row * 128 + ((sc ^ (row & 7)) << 4));
            }
            #pragma unroll
            for (int ni = 0; ni < 4; ++ni) {
                int row = wn * 64 + ni * 16 + l15;
                b[ni] = *reinterpret_cast<const short8*>(Bs + row * 128 + ((sc ^ (row & 7)) << 4));
            }
            #pragma unroll
            for (int mi = 0; mi < 8; ++mi)
                #pragma unroll
                for (int ni = 0; ni < 4; ++ni)
                    acc[mi][ni] = __builtin_amdgcn_mfma_f32_16x16x32_bf16(a[mi], b[ni], acc[mi][ni], 0, 0, 0);
        }

        asm volatile("" ::: "memory");
        __builtin_amdgcn_s_barrier();
    }

    #pragma unroll
    for (int mi = 0; mi < 8; ++mi) {
        #pragma unroll
        for (int ni = 0; ni < 4; ++ni) {
            int col = n0 + wn * 64 + ni * 16 + l15;
            float bv = BIAS ? bias[col] : 0.0f;
            #pragma unroll
            for (int r = 0; r < 4; ++r) {
                int row = m0 + wm * 128 + mi * 16 + lq * 4 + r;
                float v = acc[mi][ni][r] + bv;
                if (RELU) v = v > 0.0f ? v : 0.0f;
                if (OUTB) ((u16*)out)[(size_t)row * ldo + col] = f2b(v);
                else      ((float*)out)[(size_t)row * ldo + col] = v;
            }
        }
    }
}

// ---------- flash attention ----------
// Grid (32 bh, 8); block does qbi = 15-by then by -> exactly 34 KV-tiles
// per block (perfect balance, 1 block/CU).
__global__ __launch_bounds__(256, 2) void attn_kernel(
    const u16* __restrict__ qkv, const u16* __restrict__ vt, u16* __restrict__ att)
{
    __shared__ __align__(16) char smem[48 * 1024];
    char* Kb0 = smem;
    char* Kb1 = smem + 8192;
    char* Vb0 = smem + 16384;
    char* Vb1 = smem + 24576;
    char* Ost = smem + 32768;

    const int tid = threadIdx.x, lane = tid & 63, w = tid >> 6;
    const int l31 = lane & 31, hi = lane >> 5;
    const int bh = blockIdx.x;
    const int b = bh >> 4, h = bh & 15;
    const size_t base = (size_t)b * 2048;
    const int kcol = 1024 + h * 64;
    const u16* vtp = vt + (size_t)bh * 64 * 2048;
    const float SC = 0.03125f * 1.44269504f;   // C^-0.5 * log2(e)

    auto stage = [&](int st, char* kb, char* vb) {
        #pragma unroll
        for (int i = 0; i < 2; ++i) {
            int seg = w * 2 + i;
            int slot = seg * 64 + lane;
            int s = slot >> 3, d8p = slot & 7;
            gll16(qkv + (base + st * 64 + s) * 3072 + kcol + ((d8p ^ (s & 7)) * 8),
                  kb + seg * 1024);
            int d = s, s8p = d8p;
            gll16(vtp + (size_t)d * 2048 + st * 64 + ((s8p ^ (d & 7)) * 8),
                  vb + seg * 1024);
        }
    };

    for (int pass = 0; pass < 2; ++pass) {
        const int qbi = pass ? (int)blockIdx.y : 15 - (int)blockIdx.y;
        const int q0w = qbi * 128 + w * 32;
        const int nst = 2 * qbi + 2;
        const int qg = q0w + l31;

        // Q B-frags, pre-scaled by SC (scores come out in log2 domain)
        short8 qf[4];
        {
            const u16* qp = qkv + (base + q0w + l31) * 3072 + h * 64 + hi * 8;
            #pragma unroll
            for (int dc = 0; dc < 4; ++dc) {
                short8 q = *reinterpret_cast<const short8*>(qp + dc * 16);
                #pragma unroll
                for (int j = 0; j < 8; j += 2) {
                    u32 pk = cvtpk(b2f((u16)q[j]) * SC, b2f((u16)q[j + 1]) * SC);
                    q[j]     = (short)(pk & 0xffff);
                    q[j + 1] = (short)(pk >> 16);
                }
                qf[dc] = q;
            }
        }

        f32x16 oT[2] = {};
        float m = -1e30f, lsum = 0.0f;

        stage(0, Kb0, Vb0);
        __syncthreads();

        for (int st = 0; st < nst; ++st) {
            char* kb = (st & 1) ? Kb1 : Kb0;
            char* vb = (st & 1) ? Vb1 : Vb0;
            if (st + 1 < nst) stage(st + 1, (st & 1) ? Kb0 : Kb1, (st & 1) ? Vb0 : Vb1);

            f32x16 sa[2] = {};
            #pragma unroll
            for (int dc = 0; dc < 4; ++dc) {
                #pragma unroll
                for (int sb = 0; sb < 2; ++sb) {
                    int s = sb * 32 + l31;
                    int slot = (dc * 2 + hi) ^ (s & 7);
                    short8 kf = *reinterpret_cast<const short8*>(kb + s * 128 + slot * 16);
                    sa[sb] = __builtin_amdgcn_mfma_f32_32x32x16_bf16(kf, qf[dc], sa[sb], 0, 0, 0);
                }
            }

            if (st >= nst - 2) {
                #pragma unroll
                for (int sb = 0; sb < 2; ++sb)
                    #pragma unroll
                    for (int r = 0; r < 16; ++r) {
                        int sg = st * 64 + sb * 32 + (r & 3) + 8 * (r >> 2) + 4 * hi;
                        if (sg > qg) sa[sb][r] = -1e30f;
                    }
            }

            float t8[8];
            #pragma unroll
            for (int i = 0; i < 8; ++i)
                t8[i] = fmaxf(fmaxf(sa[0][i], sa[0][i + 8]), fmaxf(sa[1][i], sa[1][i + 8]));
            float t4a = fmaxf(t8[0], t8[4]), t4b = fmaxf(t8[1], t8[5]);
            float t4c = fmaxf(t8[2], t8[6]), t4d = fmaxf(t8[3], t8[7]);
            float mx = fmaxf(fmaxf(t4a, t4b), fmaxf(t4c, t4d));
            mx = fmaxf(mx, __shfl_xor(mx, 32));

            if (!__all(mx <= m + 8.0f)) {
                float nm = fmaxf(m, mx);
                float sf = ex2(m - nm);
                m = nm;
                lsum *= sf;
                #pragma unroll
                for (int dt = 0; dt < 2; ++dt)
                    #pragma unroll
                    for (int r = 0; r < 16; ++r) oT[dt][r] *= sf;
            }

            #pragma unroll
            for (int sb = 0; sb < 2; ++sb)
                #pragma unroll
                for (int r = 0; r < 16; ++r) sa[sb][r] = ex2(sa[sb][r] - m);
            float s8_[8];
            #pragma unroll
            for (int i = 0; i < 8; ++i)
                s8_[i] = (sa[0][i] + sa[0][i + 8]) + (sa[1][i] + sa[1][i + 8]);
            float s4a = s8_[0] + s8_[4], s4b = s8_[1] + s8_[5];
            float s4c = s8_[2] + s8_[6], s4d = s8_[3] + s8_[7];
            float ps = (s4a + s4b) + (s4c + s4d);
            ps += __shfl_xor(ps, 32);
            lsum += ps;

            u32 pkE[4][2], pkO[4][2];
            #pragma unroll
            for (int sc = 0; sc < 4; ++sc) {
                const int sb = sc >> 1, rb = 8 * (sc & 1);
                #pragma unroll
                for (int c = 0; c < 2; ++c) {
                    pkE[sc][c] = cvtpk(sa[sb][rb + 2 * c], sa[sb][rb + 2 * c + 1]);
                    pkO[sc][c] = cvtpk(sa[sb][rb + 4 + 2 * c], sa[sb][rb + 4 + 2 * c + 1]);
                }
            }

            #pragma unroll
            for (int sc = 0; sc < 4; ++sc) {
                u32 wd[4];
                #pragma unroll
                for (int ww = 0; ww < 4; ++ww) {
                    const int c = ww & 1;
                    u32 own  = hi ? pkO[sc][c] : pkE[sc][c];
                    u32 send = hi ? pkE[sc][c] : pkO[sc][c];
                    u32 ex = (u32)__shfl_xor((int)send, 32);
                    wd[ww] = ((ww >> 1) == hi) ? own : ex;
                }
                union { u32 u[4]; short8 s8; } pb_;
                pb_.u[0] = wd[0]; pb_.u[1] = wd[1]; pb_.u[2] = wd[2]; pb_.u[3] = wd[3];
                #pragma unroll
                for (int dt = 0; dt < 2; ++dt) {
                    int d = dt * 32 + l31;
                    int slot = (sc * 2 + hi) ^ (d & 7);
                    short8 vf = *reinterpret_cast<const short8*>(vb + d * 128 + slot * 16);
                    oT[dt] = __builtin_amdgcn_mfma_f32_32x32x16_bf16(vf, pb_.s8, oT[dt], 0, 0, 0);
                }
            }
            __syncthreads();
        }

        // epilogue: O^T -> per-wave LDS transpose -> coalesced store
        {
            float inv = 1.0f / lsum;
            char* ob = Ost + w * 4096;
            #pragma unroll
            for (int dt = 0; dt < 2; ++dt)
                #pragma unroll
                for (int rp = 0; rp < 8; ++rp) {
                    int r = rp * 2;
                    int d = dt * 32 + (r & 3) + 8 * (r >> 2) + 4 * hi;
                    u32 pk2 = cvtpk(oT[dt][r] * inv, oT[dt][r + 1] * inv);
                    int byte = l31 * 128 + ((((d >> 3) ^ (l31 & 7)) << 4)) + (d & 7) * 2;
                    *reinterpret_cast<u32*>(ob + byte) = pk2;
                }
            int q = lane >> 1, half = lane & 1;
            size_t grow = (base + q0w - w * 32 + (w * 32 + q)) * 1024 + h * 64 + half * 32;
            #pragma unroll
            for (int c = 0; c < 4; ++c) {
                int chunk = half * 4 + c;
                int byte = q * 128 + ((chunk ^ (q & 7)) << 4);
                float4 vv = *reinterpret_cast<const float4*>(ob + byte);
                *reinterpret_cast<float4*>(att + grow + c * 8) = vv;
            }
        }
    }
}

// ---------- launch ----------
extern "C" void kernel_launch(void* const* d_in, const int* in_sizes, int n_in,
                              void* d_out, int out_size, void* d_ws, size_t ws_size,
                              hipStream_t stream)
{
    const float* x   = (const float*)d_in[0];
    const float* Wq  = (const float*)d_in[1];
    const float* Wk  = (const float*)d_in[2];
    const float* Wv  = (const float*)d_in[3];
    const float* Wp  = (const float*)d_in[4];
    const float* bp  = (const float*)d_in[5];
    const float* W1  = (const float*)d_in[6];
    const float* b1  = (const float*)d_in[7];
    const float* W2  = (const float*)d_in[8];
    const float* b2  = (const float*)d_in[9];
    const float* g1  = (const float*)d_in[10];
    const float* be1 = (const float*)d_in[11];
    const float* g2  = (const float*)d_in[12];
    const float* be2 = (const float*)d_in[13];
    float* out = (float*)d_out;

    char* ws = (char*)d_ws;
    u16*   wqkvT = (u16*)(ws + 0);                  //  6 MiB [3072,1024]
    u16*   wpT   = (u16*)(ws + 6291456);            //  2 MiB [1024,1024]
    u16*   w1T   = (u16*)(ws + 8388608);            //  8 MiB [4096,1024]
    u16*   w2T   = (u16*)(ws + 16777216);           //  8 MiB [1024,4096]
    float* xlnF  = (float*)(ws + 25165824);         // 16 MiB
    u16*   xlnB  = (u16*)(ws + 41943040);           //  8 MiB (also yB)
    u16*   qkv   = (u16*)(ws + 50331648);           // 24 MiB
    float* x2    = (float*)(ws + 50331648);         // reuse after attn
    u16*   hbuf  = (u16*)(ws + 50331648);           // reuse after ln2
    u16*   attb  = (u16*)(ws + 75497472);           //  8 MiB
    float* yF    = (float*)(ws + 83886080);         // 16 MiB (after attn)
    u16*   vtb   = (u16*)(ws + 83886080);           //  8 MiB (before ln2)
    u16*   yB    = xlnB;

    repack_qkv_tiled<<<dim3(16, 48), 256, 0, stream>>>(Wq, Wk, Wv, wqkvT);
    trans_tiled<<<dim3(16, 16), 256, 0, stream>>>(Wp, wpT, 1024, 1024);
    trans_tiled<<<dim3(16, 64), 256, 0, stream>>>(W1, w1T, 1024, 4096);
    trans_tiled<<<dim3(64, 16), 256, 0, stream>>>(W2, w2T, 4096, 1024);

    ln_kernel<<<4096, 256, 0, stream>>>(x, g1, be1, xlnF, xlnB);

    // QKV = xln @ Wqkv -> bf16 [4096, 3072]   (256^2, 192 blocks)
    gemm_bt256<false, false, true><<<dim3(12, 16), 512, 0, stream>>>(
        xlnB, 1024, wqkvT, 1024, qkv, 3072, nullptr, 1024);

    vt_kernel<<<dim3(32, 16, 2), 256, 0, stream>>>(qkv, vtb);
    attn_kernel<<<dim3(32, 8), 256, 0, stream>>>(qkv, vtb, attb);

    gemm_bt<true, false, true, false><<<dim3(8, 32), 256, 0, stream>>>(
        attb, 1024, wpT, 1024, x2, 1024, bp, xlnF, 1024);

    ln_kernel<<<4096, 256, 0, stream>>>(x2, g2, be2, yF, yB);

    // FF1 = relu(y @ W1 + b1) -> bf16 [4096, 4096]   (256^2, 256 blocks)
    gemm_bt256<true, true, true><<<dim3(16, 16), 512, 0, stream>>>(
        yB, 1024, w1T, 1024, hbuf, 4096, b1, 1024);

    // FF2 = y + h @ W2 + b2 -> f32 [4096, 1024]
    gemm_bt<true, false, true, false><<<dim3(8, 32), 256, 0, stream>>>(
        hbuf, 4096, w2T, 4096, out, 1024, b2, yF, 4096);
}